// Round 1
// baseline (124.501 us; speedup 1.0000x reference)
//
#include <hip/hip_runtime.h>

#define H 1024
#define W 1024
#define NPIX (H * W)
#define INF_F 1e12f

// Pass 1: per-pixel vertical nearest-site squared distance, both polarities.
// g_t  = EDT^2 source for mask t  (sites where target == 0)
// g_nt = EDT^2 source for mask ~t (sites where target != 0)
// Exact: outward scan; the first site found at |dk| is the nearest.
__global__ __launch_bounds__(256) void edt_vertical(
    const int* __restrict__ target,
    float* __restrict__ g_t,
    float* __restrict__ g_nt) {
  int idx = blockIdx.x * blockDim.x + threadIdx.x;
  if (idx >= NPIX) return;
  int r = idx >> 10;  // / W
  int t0 = target[idx];
  int dz = (t0 == 0) ? 0 : -1;  // distance to nearest zero pixel (vertical)
  int dn = (t0 != 0) ? 0 : -1;  // distance to nearest nonzero pixel (vertical)
  for (int dk = 1; dk < H && (dz < 0 || dn < 0); ++dk) {
    if (r - dk >= 0) {
      int v = target[idx - dk * W];
      if (dz < 0 && v == 0) dz = dk;
      if (dn < 0 && v != 0) dn = dk;
    }
    if (r + dk < H) {
      int v = target[idx + dk * W];
      if (dz < 0 && v == 0) dz = dk;
      if (dn < 0 && v != 0) dn = dk;
    }
  }
  g_t[idx]  = (dz < 0) ? INF_F : (float)dz * (float)dz;
  g_nt[idx] = (dn < 0) ? INF_F : (float)dn * (float)dn;
}

// Pass 2: horizontal parabola envelope with exact early exit, fused with
// sd computation and the mean reduction (f64 accumulate).
__global__ __launch_bounds__(256) void edt_horiz_reduce(
    const int* __restrict__ target,
    const float* __restrict__ input,
    const float* __restrict__ g_t,
    const float* __restrict__ g_nt,
    double* __restrict__ acc) {
  int idx = blockIdx.x * blockDim.x + threadIdx.x;
  double val = 0.0;
  if (idx < NPIX) {
    int j = idx & (W - 1);
    bool t = target[idx] != 0;
    const float* __restrict__ g = t ? g_t : g_nt;
    float best = g[idx];  // k == j term (dk2 = 0)
    for (int dk = 1; dk < W; ++dk) {
      float dk2 = (float)(dk * dk);
      if (dk2 >= best) break;  // no farther k can reduce the min (g >= 0)
      if (j - dk >= 0) best = fminf(best, g[idx - dk] + dk2);
      if (j + dk < W)  best = fminf(best, g[idx + dk] + dk2);
    }
    float dist = sqrtf(best);
    // sd = inside*(1-tf) - (outside-1)*tf  ->  t ? (1 - outside) : inside
    float sd = t ? (1.0f - dist) : dist;
    val = (double)(input[idx] * sd);
  }
  // wave(64) shuffle reduction
  for (int off = 32; off > 0; off >>= 1)
    val += __shfl_down(val, off, 64);
  __shared__ double smem[4];  // 256 threads = 4 waves
  int lane = threadIdx.x & 63;
  int wid = threadIdx.x >> 6;
  if (lane == 0) smem[wid] = val;
  __syncthreads();
  if (threadIdx.x == 0) {
    double s = smem[0] + smem[1] + smem[2] + smem[3];
    atomicAdd(acc, s);
  }
}

__global__ void finalize(const double* __restrict__ acc,
                         float* __restrict__ out) {
  out[0] = (float)(acc[0] * (1.0 / (double)NPIX));
}

extern "C" void kernel_launch(void* const* d_in, const int* in_sizes, int n_in,
                              void* d_out, int out_size, void* d_ws, size_t ws_size,
                              hipStream_t stream) {
  const float* input = (const float*)d_in[0];
  const int* target = (const int*)d_in[1];
  float* out = (float*)d_out;

  // workspace layout: [0,8) f64 accumulator; g_t at +1KiB; g_nt after it.
  double* acc = (double*)d_ws;
  float* g_t = (float*)((char*)d_ws + 1024);
  float* g_nt = g_t + NPIX;

  hipMemsetAsync(acc, 0, sizeof(double), stream);

  int threads = 256;
  int blocks = (NPIX + threads - 1) / threads;
  edt_vertical<<<blocks, threads, 0, stream>>>(target, g_t, g_nt);
  edt_horiz_reduce<<<blocks, threads, 0, stream>>>(target, input, g_t, g_nt, acc);
  finalize<<<1, 1, 0, stream>>>(acc, out);
}

// Round 2
// 77.348 us; speedup vs baseline: 1.6096x; 1.6096x over previous
//
#include <hip/hip_runtime.h>

#define H 1024
#define W 1024
#define NPIX (H * W)
#define INF_F 1e12f
#define THREADS 256
#define NBLK (NPIX / THREADS)  // 4096
#define RHALO 32               // LDS halo radius for horizontal probes

// ---------------------------------------------------------------------------
// Pass 1: per-pixel vertical nearest-site squared distance, both polarities.
// Batched x4 probes to shorten the dependent-load chain (exact: first hit at
// smallest dk wins; batches scanned in order).
// ---------------------------------------------------------------------------
__global__ __launch_bounds__(THREADS) void edt_vertical(
    const int* __restrict__ target,
    float* __restrict__ g_t,
    float* __restrict__ g_nt) {
  int idx = blockIdx.x * THREADS + threadIdx.x;
  int r = idx >> 10;  // / W
  int t0 = target[idx];
  int dz = (t0 == 0) ? 0 : -1;  // vertical distance to nearest zero pixel
  int dn = (t0 != 0) ? 0 : -1;  // vertical distance to nearest nonzero pixel
  for (int base = 1; (dz | dn) < 0 && base < H; base += 4) {
#pragma unroll
    for (int u = 0; u < 4; ++u) {
      int dk = base + u;
      int vu = (r >= dk) ? target[idx - dk * W] : -1;      // -1: OOB, matches neither
      int vd = (r + dk < H) ? target[idx + dk * W] : -1;
      if (dz < 0 && (vu == 0 || vd == 0)) dz = dk;
      if (dn < 0 && (vu > 0 || vd > 0)) dn = dk;
    }
  }
  g_t[idx]  = (dz < 0) ? INF_F : (float)(dz * dz);
  g_nt[idx] = (dn < 0) ? INF_F : (float)(dn * dn);
}

// ---------------------------------------------------------------------------
// Pass 2: horizontal parabola lower-envelope, LDS-staged with halo, batched
// probes, fused sd + product, per-block partial sum (NO global atomics).
// ---------------------------------------------------------------------------
__global__ __launch_bounds__(THREADS) void edt_horiz(
    const int* __restrict__ target,
    const float* __restrict__ input,
    const float* __restrict__ g_t,
    const float* __restrict__ g_nt,
    double* __restrict__ partials) {
  __shared__ float sg2[2][THREADS + 2 * RHALO];  // [0]=g_t, [1]=g_nt
  const int tid = threadIdx.x;
  const int idx = blockIdx.x * THREADS + tid;
  const int j = idx & (W - 1);
  const int row0 = idx & ~(W - 1);
  const int cstart = (blockIdx.x * THREADS) & (W - 1);

  // stage g_t/g_nt span [cstart-RHALO, cstart+THREADS+RHALO) clamped to row
  for (int e = tid; e < THREADS + 2 * RHALO; e += THREADS) {
    int c = cstart - RHALO + e;
    bool ok = (c >= 0) && (c < W);
    int gi = row0 + (ok ? c : 0);
    sg2[0][e] = ok ? g_t[gi] : INF_F;
    sg2[1][e] = ok ? g_nt[gi] : INF_F;
  }
  __syncthreads();

  const bool t = target[idx] != 0;
  const float* __restrict__ sg = &sg2[t ? 0 : 1][0];
  const int lj = tid + RHALO;

  float best = sg[lj];  // k == j term
  // batched LDS probes, dk in [1, RHALO]; exact early exit per batch
  for (int base = 1; base + 3 <= RHALO; base += 4) {
    if ((float)(base * base) >= best) break;
#pragma unroll
    for (int u = 0; u < 4; ++u) {
      int dk = base + u;
      float dk2 = (float)(dk * dk);
      best = fminf(best, sg[lj - dk] + dk2);
      best = fminf(best, sg[lj + dk] + dk2);
    }
  }
  // exact fallback beyond the halo (astronomically rare at p=0.5)
  if ((float)((RHALO + 1) * (RHALO + 1)) < best) {
    const float* __restrict__ g = t ? g_t : g_nt;
    for (int dk = RHALO + 1; dk < W; ++dk) {
      float dk2 = (float)(dk * dk);
      if (dk2 >= best) break;
      if (j - dk >= 0) best = fminf(best, g[row0 + j - dk] + dk2);
      if (j + dk < W)  best = fminf(best, g[row0 + j + dk] + dk2);
    }
  }

  float dist = sqrtf(best);
  float sd = t ? (1.0f - dist) : dist;  // inside*(1-tf) - (outside-1)*tf
  double val = (double)(input[idx] * sd);

  // block reduction -> partials[blockIdx.x]
  for (int off = 32; off > 0; off >>= 1)
    val += __shfl_down(val, off, 64);
  __shared__ double smem[THREADS / 64];
  int lane = tid & 63, wid = tid >> 6;
  if (lane == 0) smem[wid] = val;
  __syncthreads();
  if (tid == 0)
    partials[blockIdx.x] = smem[0] + smem[1] + smem[2] + smem[3];
}

// ---------------------------------------------------------------------------
// Final: sum 4096 partials, divide, write scalar.
// ---------------------------------------------------------------------------
__global__ __launch_bounds__(THREADS) void reduce_partials(
    const double* __restrict__ partials, float* __restrict__ out) {
  double s = 0.0;
  for (int i = threadIdx.x; i < NBLK; i += THREADS) s += partials[i];
  for (int off = 32; off > 0; off >>= 1)
    s += __shfl_down(s, off, 64);
  __shared__ double smem[THREADS / 64];
  int lane = threadIdx.x & 63, wid = threadIdx.x >> 6;
  if (lane == 0) smem[wid] = s;
  __syncthreads();
  if (threadIdx.x == 0)
    out[0] = (float)((smem[0] + smem[1] + smem[2] + smem[3]) / (double)NPIX);
}

extern "C" void kernel_launch(void* const* d_in, const int* in_sizes, int n_in,
                              void* d_out, int out_size, void* d_ws, size_t ws_size,
                              hipStream_t stream) {
  const float* input = (const float*)d_in[0];
  const int* target = (const int*)d_in[1];
  float* out = (float*)d_out;

  // workspace: [0, 32KiB) partials[4096]; then g_t, g_nt (4 MiB each)
  double* partials = (double*)d_ws;
  float* g_t = (float*)((char*)d_ws + 32 * 1024);
  float* g_nt = g_t + NPIX;

  edt_vertical<<<NBLK, THREADS, 0, stream>>>(target, g_t, g_nt);
  edt_horiz<<<NBLK, THREADS, 0, stream>>>(target, input, g_t, g_nt, partials);
  reduce_partials<<<1, THREADS, 0, stream>>>(partials, out);
}

// Round 3
// 69.594 us; speedup vs baseline: 1.7890x; 1.1114x over previous
//
#include <hip/hip_runtime.h>

#define H 1024
#define W 1024
#define NPIX (H * W)
#define WW 16          // 64-row words per column
#define INF_F 1e12f
#define THREADS 256
#define BIG (1 << 29)

// ---------------------------------------------------------------------------
// Exact vertical nearest-site distance for pixel (r,c), polarity pol
// (pol=1: sites are 1-pixels; pol=0: sites are 0-pixels). Cold path.
// Returns >= 2^30 if the column has no site of that polarity.
// ---------------------------------------------------------------------------
__device__ __noinline__ int vert_dist_full(const unsigned long long* __restrict__ pw,
                                           int r, int c, int pol) {
  int w = r >> 6, b = r & 63;
  unsigned long long v = pw[w * W + c];
  unsigned long long m_c = pol ? v : ~v;
  int dup = 1 << 30, ddn = 1 << 30;
  unsigned long long am = m_c & ((1ULL << b) - 1ULL);
  if (am) {
    dup = b - (63 - __builtin_clzll(am));
  } else {
    for (int ww = w - 1; ww >= 0; --ww) {
      unsigned long long mv = pw[ww * W + c];
      mv = pol ? mv : ~mv;
      if (mv) { dup = r - (ww * 64 + 63 - __builtin_clzll(mv)); break; }
    }
  }
  unsigned long long bm = m_c >> b;  // includes self
  if (bm) {
    ddn = __builtin_ctzll(bm);
  } else {
    for (int ww = w + 1; ww < WW; ++ww) {
      unsigned long long mv = pw[ww * W + c];
      mv = pol ? mv : ~mv;
      if (mv) { ddn = (ww * 64 + __builtin_ctzll(mv)) - r; break; }
    }
  }
  return min(dup, ddn);
}

// Cold exact continuation of the parabola min beyond the LDS halo (or full
// restart when byte-sentinel ambiguity is possible). Never taken at p=0.5.
__device__ __noinline__ int horiz_exact(const unsigned long long* __restrict__ pw,
                                        int r, int c, int pol, int best, int dk0) {
  for (int dk = dk0; dk < W; ++dk) {
    int dk2 = dk * dk;
    if (dk2 >= best) break;
    if (c - dk >= 0) {
      int d = vert_dist_full(pw, r, c - dk, pol);
      if (d < H) best = min(best, d * d + dk2);
    }
    if (c + dk < W) {
      int d = vert_dist_full(pw, r, c + dk, pol);
      if (d < H) best = min(best, d * d + dk2);
    }
  }
  return best;
}

// ---------------------------------------------------------------------------
// Kernel A: pack target (0/1 int32) into a bit matrix, column-major bits:
// pw[w*W + c] bit b = (target[(w*64+b)*W + c] != 0). Stored as u32 halves.
// ---------------------------------------------------------------------------
__global__ __launch_bounds__(THREADS) void pack_bits(
    const int* __restrict__ target, unsigned int* __restrict__ pw32) {
  int tg = blockIdx.x * THREADS + threadIdx.x;  // 32768 threads
  int w = tg >> 11;
  int half = (tg >> 10) & 1;
  int c = tg & (W - 1);
  int rbase = w * 64 + half * 32;
  unsigned int val = 0;
#pragma unroll
  for (int b = 0; b < 32; ++b) {
    if (target[(rbase + b) * W + c] != 0) val |= (1u << b);
  }
  pw32[((w * W + c) << 1) + half] = val;
}

// ---------------------------------------------------------------------------
// Kernel B: fused vertical EDT (bit ops) + horizontal parabola envelope (LDS
// bytes) + input*sd product + per-block reduction. 4 rows per block.
// ---------------------------------------------------------------------------
__global__ __launch_bounds__(THREADS) void fused_edt(
    const unsigned long long* __restrict__ pw,
    const float* __restrict__ input,
    double* __restrict__ partials) {
  // byte distances, [pol*4 + rr][32 + c]; 255 = "d >= 255" sentinel / border
  __shared__ unsigned char sd8[8][W + 64];
  const int tid = threadIdx.x;
  const int r0 = blockIdx.x << 2;  // 4 rows per block
  const int w = r0 >> 6, b0 = r0 & 63;
  const int c0 = tid << 2;         // 4 consecutive columns per thread

  // border init: 16 pad-u32 per plane x 8 planes = 128 u32
  if (tid < 128) {
    int p = tid >> 4, q = tid & 15;
    ((unsigned int*)sd8)[p * 272 + (q < 8 ? q : 256 + q)] = 0xFFFFFFFFu;
  }

  // ---- phase 1: vertical distances for 4 cols x 4 rows, both polarities ----
  unsigned long long curv[4], prevv[4], nextv[4];
  *(ulonglong2*)&curv[0] = *(const ulonglong2*)(pw + w * W + c0);
  *(ulonglong2*)&curv[2] = *(const ulonglong2*)(pw + w * W + c0 + 2);
  const bool hp = (w > 0), hn = (w < WW - 1);
  if (hp) {
    *(ulonglong2*)&prevv[0] = *(const ulonglong2*)(pw + (w - 1) * W + c0);
    *(ulonglong2*)&prevv[2] = *(const ulonglong2*)(pw + (w - 1) * W + c0 + 2);
  } else prevv[0] = prevv[1] = prevv[2] = prevv[3] = 0ULL;
  if (hn) {
    *(ulonglong2*)&nextv[0] = *(const ulonglong2*)(pw + (w + 1) * W + c0);
    *(ulonglong2*)&nextv[2] = *(const ulonglong2*)(pw + (w + 1) * W + c0 + 2);
  } else nextv[0] = nextv[1] = nextv[2] = nextv[3] = 0ULL;

  unsigned char dloc[2][4][4];  // [pol][rr][k]
#pragma unroll
  for (int pol = 0; pol < 2; ++pol) {
#pragma unroll
    for (int k = 0; k < 4; ++k) {
      unsigned long long m_c = pol ? curv[k] : ~curv[k];
      unsigned long long m_p = hp ? (pol ? prevv[k] : ~prevv[k]) : 0ULL;
      unsigned long long m_n = hn ? (pol ? nextv[k] : ~nextv[k]) : 0ULL;
#pragma unroll
      for (int rr = 0; rr < 4; ++rr) {
        int b = b0 + rr;
        int d = 1 << 30;
        unsigned long long am = m_c & ((1ULL << b) - 1ULL);
        if (am) d = b - (63 - __builtin_clzll(am));
        else if (m_p) d = b + 1 + __builtin_clzll(m_p);
        unsigned long long bm = m_c >> b;  // includes self
        int dd = 1 << 30;
        if (bm) dd = __builtin_ctzll(bm);
        else if (m_n) dd = (64 - b) + __builtin_ctzll(m_n);
        d = min(d, dd);
        if (d > 64) d = vert_dist_full(pw, r0 + rr, c0 + k, pol);  // cold
        dloc[pol][rr][k] = (unsigned char)min(d, 255);
      }
    }
  }
  // LDS store: pack 4 col-bytes -> one u32 per (pol,rr); conflict-free
#pragma unroll
  for (int pol = 0; pol < 2; ++pol)
#pragma unroll
    for (int rr = 0; rr < 4; ++rr) {
      unsigned int u = (unsigned int)dloc[pol][rr][0] |
                       ((unsigned int)dloc[pol][rr][1] << 8) |
                       ((unsigned int)dloc[pol][rr][2] << 16) |
                       ((unsigned int)dloc[pol][rr][3] << 24);
      *(unsigned int*)&sd8[pol * 4 + rr][32 + c0] = u;
    }
  __syncthreads();

  // ---- phase 2: horizontal envelope + product ----
  double val = 0.0;
#pragma unroll
  for (int rr = 0; rr < 4; ++rr) {
    const float4 iv = *(const float4*)(input + (r0 + rr) * W + c0);
    const float ivk[4] = {iv.x, iv.y, iv.z, iv.w};
#pragma unroll
    for (int k = 0; k < 4; ++k) {
      const bool t = (dloc[1][rr][k] == 0);  // nearest-one dist 0 <=> t=1
      const int pol = t ? 0 : 1;             // t uses g_t (nearest zero)
      const int own = t ? dloc[0][rr][k] : dloc[1][rr][k];
      int best = (own == 255) ? BIG : own * own;
      const unsigned char* __restrict__ sg = &sd8[pol * 4 + rr][32 + c0 + k];
      for (int dk = 1; dk <= 32; ++dk) {
        int dk2 = dk * dk;
        if (dk2 >= best) break;
        int dl = sg[-dk], dr = sg[dk];
        int gl = (dl == 255) ? BIG : dl * dl;
        int gr = (dr == 255) ? BIG : dr * dr;
        best = min(best, min(gl, gr) + dk2);
      }
      if (best > 1089) {  // cold exact fallback
        int r = r0 + rr, c = c0 + k;
        if (best > 65025) {  // sentinel could have hidden a true min
          int ov = vert_dist_full(pw, r, c, pol);
          best = (ov < H) ? ov * ov : (1 << 30);
          best = horiz_exact(pw, r, c, pol, best, 1);
        } else {
          best = horiz_exact(pw, r, c, pol, best, 33);
        }
      }
      float bestf = (best >= BIG) ? INF_F : (float)best;
      float dist = sqrtf(bestf);
      float sd = t ? (1.0f - dist) : dist;
      val += (double)(ivk[k] * sd);
    }
  }

  // ---- phase 3: block reduction ----
  for (int off = 32; off > 0; off >>= 1)
    val += __shfl_down(val, off, 64);
  __shared__ double smem[THREADS / 64];
  int lane = tid & 63, wid = tid >> 6;
  if (lane == 0) smem[wid] = val;
  __syncthreads();
  if (tid == 0)
    partials[blockIdx.x] = smem[0] + smem[1] + smem[2] + smem[3];
}

// ---------------------------------------------------------------------------
// Kernel C: reduce 256 partials -> mean scalar.
// ---------------------------------------------------------------------------
__global__ __launch_bounds__(THREADS) void reduce_partials(
    const double* __restrict__ partials, float* __restrict__ out) {
  double s = partials[threadIdx.x];
  for (int off = 32; off > 0; off >>= 1)
    s += __shfl_down(s, off, 64);
  __shared__ double smem[THREADS / 64];
  int lane = threadIdx.x & 63, wid = threadIdx.x >> 6;
  if (lane == 0) smem[wid] = s;
  __syncthreads();
  if (threadIdx.x == 0)
    out[0] = (float)((smem[0] + smem[1] + smem[2] + smem[3]) / (double)NPIX);
}

extern "C" void kernel_launch(void* const* d_in, const int* in_sizes, int n_in,
                              void* d_out, int out_size, void* d_ws, size_t ws_size,
                              hipStream_t stream) {
  const float* input = (const float*)d_in[0];
  const int* target = (const int*)d_in[1];
  float* out = (float*)d_out;

  // workspace: [0,2KiB) partials[256]; pw (128 KiB) at +4KiB
  double* partials = (double*)d_ws;
  unsigned long long* pw = (unsigned long long*)((char*)d_ws + 4096);

  pack_bits<<<128, THREADS, 0, stream>>>(target, (unsigned int*)pw);
  fused_edt<<<H / 4, THREADS, 0, stream>>>(pw, input, partials);
  reduce_partials<<<1, THREADS, 0, stream>>>(partials, out);
}

// Round 4
// 66.599 us; speedup vs baseline: 1.8694x; 1.0450x over previous
//
#include <hip/hip_runtime.h>

#define H 1024
#define W 1024
#define NPIX (H * W)
#define WW 16          // 64-row words per column
#define INF_F 1e12f
#define THREADS 256
#define BIG (1 << 29)

// ---------------------------------------------------------------------------
// Exact vertical nearest-site distance for pixel (r,c), polarity pol
// (pol=1: sites are 1-pixels; pol=0: sites are 0-pixels). Cold path.
// ---------------------------------------------------------------------------
__device__ __noinline__ int vert_dist_full(const unsigned long long* __restrict__ pw,
                                           int r, int c, int pol) {
  int w = r >> 6, b = r & 63;
  unsigned long long v = pw[w * W + c];
  unsigned long long m_c = pol ? v : ~v;
  int dup = 1 << 30, ddn = 1 << 30;
  unsigned long long am = m_c & ((1ULL << b) - 1ULL);
  if (am) {
    dup = b - (63 - __builtin_clzll(am));
  } else {
    for (int ww = w - 1; ww >= 0; --ww) {
      unsigned long long mv = pw[ww * W + c];
      mv = pol ? mv : ~mv;
      if (mv) { dup = r - (ww * 64 + 63 - __builtin_clzll(mv)); break; }
    }
  }
  unsigned long long bm = m_c >> b;  // includes self
  if (bm) {
    ddn = __builtin_ctzll(bm);
  } else {
    for (int ww = w + 1; ww < WW; ++ww) {
      unsigned long long mv = pw[ww * W + c];
      mv = pol ? mv : ~mv;
      if (mv) { ddn = (ww * 64 + __builtin_ctzll(mv)) - r; break; }
    }
  }
  return min(dup, ddn);
}

// Cold exact continuation/restart of the parabola min. Never taken at p=0.5.
__device__ __noinline__ int horiz_exact(const unsigned long long* __restrict__ pw,
                                        int r, int c, int pol, int best, int dk0) {
  for (int dk = dk0; dk < W; ++dk) {
    int dk2 = dk * dk;
    if (dk2 >= best) break;
    if (c - dk >= 0) {
      int d = vert_dist_full(pw, r, c - dk, pol);
      if (d < H) best = min(best, d * d + dk2);
    }
    if (c + dk < W) {
      int d = vert_dist_full(pw, r, c + dk, pol);
      if (d < H) best = min(best, d * d + dk2);
    }
  }
  return best;
}

// ---------------------------------------------------------------------------
// Kernel A: pack target (0/1 int32) into a bit matrix, column-major bits:
// pw[w*W + c] bit b = (target[(w*64+b)*W + c] != 0). Stored as u32 halves.
// ---------------------------------------------------------------------------
__global__ __launch_bounds__(THREADS) void pack_bits(
    const int* __restrict__ target, unsigned int* __restrict__ pw32) {
  int tg = blockIdx.x * THREADS + threadIdx.x;  // 32768 threads
  int w = tg >> 11;
  int half = (tg >> 10) & 1;
  int c = tg & (W - 1);
  int rbase = w * 64 + half * 32;
  unsigned int val = 0;
#pragma unroll
  for (int b = 0; b < 32; ++b) {
    if (target[(rbase + b) * W + c] != 0) val |= (1u << b);
  }
  pw32[((w * W + c) << 1) + half] = val;
}

// ---------------------------------------------------------------------------
// Kernel B: fused vertical EDT (bit ops) + horizontal parabola envelope (LDS
// bytes) + input*sd product + per-block reduction. ONE row per block (1024
// blocks -> 4 blocks/CU, 16 waves/CU for latency hiding).
// ---------------------------------------------------------------------------
__global__ __launch_bounds__(THREADS) void fused_edt_row(
    const unsigned long long* __restrict__ pw,
    const float* __restrict__ input,
    double* __restrict__ partials) {
  // byte distances, [pol][32 + c]; 255 = "d >= 255" sentinel / border pad
  __shared__ unsigned char sd8[2][W + 64];
  const int tid = threadIdx.x;
  const int r = blockIdx.x;
  const int w = r >> 6, b = r & 63;  // wave-uniform
  const int c0 = tid << 2;           // 4 consecutive columns per thread

  // border init: 2 planes x 16 pad-u32 (8 left + 8 right)
  if (tid < 32) {
    int p = tid >> 4, q = tid & 15;
    ((unsigned int*)sd8)[p * 272 + (q < 8 ? q : 256 + q)] = 0xFFFFFFFFu;
  }

  // ---- phase 1: vertical distances for 4 cols, both polarities ----
  unsigned long long curv[4], prevv[4], nextv[4];
  *(ulonglong2*)&curv[0] = *(const ulonglong2*)(pw + w * W + c0);
  *(ulonglong2*)&curv[2] = *(const ulonglong2*)(pw + w * W + c0 + 2);
  const bool hp = (w > 0), hn = (w < WW - 1);
  if (hp) {
    *(ulonglong2*)&prevv[0] = *(const ulonglong2*)(pw + (w - 1) * W + c0);
    *(ulonglong2*)&prevv[2] = *(const ulonglong2*)(pw + (w - 1) * W + c0 + 2);
  } else prevv[0] = prevv[1] = prevv[2] = prevv[3] = 0ULL;
  if (hn) {
    *(ulonglong2*)&nextv[0] = *(const ulonglong2*)(pw + (w + 1) * W + c0);
    *(ulonglong2*)&nextv[2] = *(const ulonglong2*)(pw + (w + 1) * W + c0 + 2);
  } else nextv[0] = nextv[1] = nextv[2] = nextv[3] = 0ULL;

  unsigned char dloc[2][4];  // [pol][k]
#pragma unroll
  for (int pol = 0; pol < 2; ++pol) {
#pragma unroll
    for (int k = 0; k < 4; ++k) {
      unsigned long long m_c = pol ? curv[k] : ~curv[k];
      unsigned long long m_p = hp ? (pol ? prevv[k] : ~prevv[k]) : 0ULL;
      unsigned long long m_n = hn ? (pol ? nextv[k] : ~nextv[k]) : 0ULL;
      int d = 1 << 30;
      unsigned long long am = m_c & ((1ULL << b) - 1ULL);
      if (am) d = b - (63 - __builtin_clzll(am));
      else if (m_p) d = b + 1 + __builtin_clzll(m_p);
      unsigned long long bm = m_c >> b;  // includes self
      int dd = 1 << 30;
      if (bm) dd = __builtin_ctzll(bm);
      else if (m_n) dd = (64 - b) + __builtin_ctzll(m_n);
      d = min(d, dd);
      // d in-window values are exact per direction; any d>64 must be
      // re-resolved exactly (other direction's window may have been blind)
      if (d > 64) d = vert_dist_full(pw, r, c0 + k, pol);  // cold (~2^-64)
      dloc[pol][k] = (unsigned char)min(d, 255);
    }
  }
  // LDS store: pack 4 col-bytes -> one u32 per pol; conflict-free
#pragma unroll
  for (int pol = 0; pol < 2; ++pol) {
    unsigned int u = (unsigned int)dloc[pol][0] |
                     ((unsigned int)dloc[pol][1] << 8) |
                     ((unsigned int)dloc[pol][2] << 16) |
                     ((unsigned int)dloc[pol][3] << 24);
    *(unsigned int*)&sd8[pol][32 + c0] = u;
  }
  __syncthreads();

  // ---- phase 2: horizontal envelope + product ----
  double val = 0.0;
  const float4 iv = *(const float4*)(input + r * W + c0);
  const float ivk[4] = {iv.x, iv.y, iv.z, iv.w};
#pragma unroll
  for (int k = 0; k < 4; ++k) {
    const bool t = (dloc[1][k] == 0);  // nearest-one dist 0 <=> t=1
    const int pol = t ? 0 : 1;         // t uses g_t (nearest zero)
    const int own = dloc[pol][k];
    int best = (own == 255) ? BIG : own * own;
    const unsigned char* __restrict__ sg = &sd8[pol][32 + c0 + k];
    // dk=1,2 unconditionally (branchless; extra probes preserve exactness)
#pragma unroll
    for (int dk = 1; dk <= 2; ++dk) {
      int dl = sg[-dk], dr = sg[dk];
      int gl = (dl == 255) ? BIG : dl * dl;
      int gr = (dr == 255) ? BIG : dr * dr;
      best = min(best, min(gl, gr) + dk * dk);
    }
    for (int dk = 3; dk <= 32; ++dk) {
      int dk2 = dk * dk;
      if (dk2 >= best) break;
      int dl = sg[-dk], dr = sg[dk];
      int gl = (dl == 255) ? BIG : dl * dl;
      int gr = (dr == 255) ? BIG : dr * dr;
      best = min(best, min(gl, gr) + dk2);
    }
    if (best > 1089) {  // cold exact fallback (beyond halo / sentinel)
      int c = c0 + k;
      if (best > 65025) {  // 255-sentinel could have hidden a true min
        int ov = vert_dist_full(pw, r, c, pol);
        best = (ov < H) ? ov * ov : (1 << 30);
        best = horiz_exact(pw, r, c, pol, best, 1);
      } else {
        best = horiz_exact(pw, r, c, pol, best, 33);
      }
    }
    float bestf = (best >= BIG) ? INF_F : (float)best;
    float dist = sqrtf(bestf);
    float sd = t ? (1.0f - dist) : dist;
    val += (double)(ivk[k] * sd);
  }

  // ---- phase 3: block reduction ----
  for (int off = 32; off > 0; off >>= 1)
    val += __shfl_down(val, off, 64);
  __shared__ double smem[THREADS / 64];
  int lane = tid & 63, wid = tid >> 6;
  if (lane == 0) smem[wid] = val;
  __syncthreads();
  if (tid == 0)
    partials[blockIdx.x] = smem[0] + smem[1] + smem[2] + smem[3];
}

// ---------------------------------------------------------------------------
// Kernel C: reduce 1024 partials -> mean scalar.
// ---------------------------------------------------------------------------
__global__ __launch_bounds__(THREADS) void reduce_partials(
    const double* __restrict__ partials, float* __restrict__ out) {
  double s = 0.0;
#pragma unroll
  for (int i = 0; i < 4; ++i) s += partials[threadIdx.x + i * THREADS];
  for (int off = 32; off > 0; off >>= 1)
    s += __shfl_down(s, off, 64);
  __shared__ double smem[THREADS / 64];
  int lane = threadIdx.x & 63, wid = threadIdx.x >> 6;
  if (lane == 0) smem[wid] = s;
  __syncthreads();
  if (threadIdx.x == 0)
    out[0] = (float)((smem[0] + smem[1] + smem[2] + smem[3]) / (double)NPIX);
}

extern "C" void kernel_launch(void* const* d_in, const int* in_sizes, int n_in,
                              void* d_out, int out_size, void* d_ws, size_t ws_size,
                              hipStream_t stream) {
  const float* input = (const float*)d_in[0];
  const int* target = (const int*)d_in[1];
  float* out = (float*)d_out;

  // workspace: [0,8KiB) partials[1024]; pw (128 KiB) at +8KiB
  double* partials = (double*)d_ws;
  unsigned long long* pw = (unsigned long long*)((char*)d_ws + 8192);

  pack_bits<<<128, THREADS, 0, stream>>>(target, (unsigned int*)pw);
  fused_edt_row<<<H, THREADS, 0, stream>>>(pw, input, partials);
  reduce_partials<<<1, THREADS, 0, stream>>>(partials, out);
}